// Round 5
// baseline (348.901 us; speedup 1.0000x reference)
//
#include <hip/hip_runtime.h>
#include <stdint.h>

// Problem constants (B, DIM, H, W) = (8, 256, 64, 64), HEADS=4
#define BATCH 8
#define DIM   256
#define NTOK  4096   // H*W
#define NH    4

using bf16x8  = __attribute__((ext_vector_type(8))) __bf16;
using short4v = __attribute__((ext_vector_type(4))) short;
using f32x4   = __attribute__((ext_vector_type(4))) float;

__device__ __forceinline__ short f2bf(float f) {
  union { float f; uint32_t u; } v; v.f = f;
  uint32_t r = v.u + 0x7fffu + ((v.u >> 16) & 1u);   // RNE
  return (short)(r >> 16);
}

// XCD-bijective swizzle (nwg % 8 == 0): contiguous runs of nwg/8 per XCD.
__device__ __forceinline__ int xcd_swz(int x, int nwg) {
  const int cpx = nwg >> 3;
  return (x & 7) * cpx + (x >> 3);
}

// ---------------- shared GEMM core (2-phase double-buffered) ----------------
// C[128][128] (f32 acc) = A[128 x K] * B[128 x K]^T, both operands K-major bf16.
// 256 threads = 4 waves in 2x2, each wave owns a 64x64 quadrant (4x4 frags of 16x16).
// mfma_f32_16x16x32_bf16 C/D: row=(l>>4)*4+r, col=l&15  [learn_hip m89-verified].
#define BK 32
#define TSZ (128 * BK)   // one tile, in shorts (8 KB)

__device__ __forceinline__ void stage_tile(const short* g, short* lds, int ld, int tid) {
  // 128 rows x 32 cols bf16 (8 KB) via global_load_lds width=16.
  const int wave = tid >> 6, lane = tid & 63;
#pragma unroll
  for (int r = 0; r < 2; ++r) {
    const int chunk = wave * 2 + r;                       // 0..7, 16 rows each
    const short* src = g + (size_t)(chunk * 16 + (lane >> 2)) * ld + (lane & 3) * 8;
    __builtin_amdgcn_global_load_lds(
        (const __attribute__((address_space(1))) void*)src,
        (__attribute__((address_space(3))) void*)(lds + chunk * 512),
        16, 0, 0);
  }
}

__device__ __forceinline__ void gemm_core(const short* Ag, const short* Bg, int K,
                                          int lda, int ldb,
                                          f32x4 acc[4][4], short* As, short* Bs) {
  const int tid  = threadIdx.x;
  const int lane = tid & 63;
  const int wave = tid >> 6;
  const int wm = (wave >> 1) * 64, wn = (wave & 1) * 64;
  const int l15 = lane & 15, kg = (lane >> 4) * 8;
  stage_tile(Ag, As, lda, tid);
  stage_tile(Bg, Bs, ldb, tid);
  int cur = 0;
  for (int k0 = 0; k0 < K; k0 += BK) {
    __syncthreads();                 // publish tile k0 (drains its loads)
    const int nxt = cur ^ 1;
    if (k0 + BK < K) {               // prefetch next tile into the other buffer
      stage_tile(Ag + k0 + BK, As + nxt * TSZ, lda, tid);
      stage_tile(Bg + k0 + BK, Bs + nxt * TSZ, ldb, tid);
    }
    const short* Ac = As + cur * TSZ;
    const short* Bc = Bs + cur * TSZ;
    bf16x8 af[4], bfr[4];
#pragma unroll
    for (int i = 0; i < 4; ++i)
      af[i] = *(const bf16x8*)(Ac + (wm + i * 16 + l15) * BK + kg);
#pragma unroll
    for (int j = 0; j < 4; ++j)
      bfr[j] = *(const bf16x8*)(Bc + (wn + j * 16 + l15) * BK + kg);
#pragma unroll
    for (int i = 0; i < 4; ++i)
#pragma unroll
      for (int j = 0; j < 4; ++j)
        acc[i][j] = __builtin_amdgcn_mfma_f32_16x16x32_bf16(af[i], bfr[j], acc[i][j], 0, 0, 0);
    cur = nxt;
  }
}

// ---------------- kernel 1: weight prep ----------------
// wqkv f32[3072][256] -> bf16 same layout.
// wout f32[256][1024] -> WoR2 bf16[o][h*256+c] = wout[o][c*4+h]
__global__ void prep_w(const float* __restrict__ wqkv, const float* __restrict__ wout,
                       short* __restrict__ wbf, short* __restrict__ woR2) {
  int i = blockIdx.x * 256 + threadIdx.x;
  if (i < 3072 * 256) wbf[i] = f2bf(wqkv[i]);
  if (i < 256 * 1024) {
    int o = i >> 10, k = i & 1023, h = k >> 8, c = k & 255;
    woR2[i] = f2bf(wout[o * 1024 + c * 4 + h]);
  }
}

// ---------------- kernel 2: x[b][c][n] f32 -> xT[b][n][c] bf16 (vectorized) ----------------
__global__ void __launch_bounds__(256)
transpose_x(const float* __restrict__ x, short* __restrict__ xT) {
  __shared__ short tile[64][68];               // +4 pad breaks bank conflicts
  const int b  = blockIdx.y;
  const int c0 = (blockIdx.x >> 6) * 64;
  const int n0 = (blockIdx.x & 63) * 64;
  const int t  = threadIdx.x;
  const float* xp = x + (size_t)b * DIM * NTOK;
  // load: 64 c-rows x 64 n-cols, float4 per thread, 4 iters
#pragma unroll
  for (int r = 0; r < 4; ++r) {
    int c = r * 16 + (t >> 4);
    int n = (t & 15) * 4;
    f32x4 v4 = *(const f32x4*)(xp + (size_t)(c0 + c) * NTOK + n0 + n);
#pragma unroll
    for (int u = 0; u < 4; ++u) tile[c][n + u] = f2bf(v4[u]);
  }
  __syncthreads();
  short* xo = xT + (size_t)b * NTOK * DIM;
  // store: 64 n-rows x 64 c-cols, short4 per thread, 4 iters
#pragma unroll
  for (int r = 0; r < 4; ++r) {
    int n = r * 16 + (t >> 4);
    int c = (t & 15) * 4;
    short4v o4;
#pragma unroll
    for (int u = 0; u < 4; ++u) o4[u] = tile[c + u][n];
    *(short4v*)(xo + (size_t)(n0 + n) * DIM + c0 + c) = o4;
  }
}

// ---------------- kernel 3: fused QKV projection ----------------
// blocks 0..511:   qk part, A=xT (M=n), B=Wqk (N=o) -> C[n][o], store q/k[o][n]
// blocks 512..767: v part,  A=Wv, B=xT -> C[o][n], store vT[n][c]
__global__ void __launch_bounds__(256, 4)
qkv_fused(const short* __restrict__ Wqk, const short* __restrict__ Wv,
          const short* __restrict__ xT,
          short* __restrict__ qb, short* __restrict__ kb, short* __restrict__ vT) {
  __shared__ __align__(16) short As[2 * TSZ], Bs[2 * TSZ];
  const int b = blockIdx.y;
  const int bx = xcd_swz(blockIdx.x, 768);
  const short* xTb = xT + (size_t)b * NTOK * 256;
  const int lane = threadIdx.x & 63, wave = threadIdx.x >> 6;
  const int wm = (wave >> 1) * 64, wn = (wave & 1) * 64;
  f32x4 acc[4][4] = {};

  if (bx < 512) {                          // ---- q/k path ----
    const int mtile = bx >> 4;             // 32 n-tiles
    const int ntile = bx & 15;             // 16 o-tiles
    gemm_core(xTb + (size_t)mtile * 128 * 256, Wqk + (size_t)ntile * 128 * 256,
              256, 256, 256, acc, As, Bs);
    const int o0 = ntile * 128;
    const int which = o0 >> 10;            // 0=q, 1=k (block-uniform)
    short* dst = (which == 0) ? qb : kb;
    const float scl = (which == 0) ? 0.0625f : 1.0f;
    const size_t base = (size_t)b * 1024 * NTOK;
#pragma unroll
    for (int i = 0; i < 4; ++i)
#pragma unroll
      for (int j = 0; j < 4; ++j) {
        int nbase = mtile * 128 + wm + i * 16 + ((lane >> 4) << 2);
        int o     = o0 + wn + j * 16 + (lane & 15);
        short4v o4;
#pragma unroll
        for (int r = 0; r < 4; ++r) o4[r] = f2bf(acc[i][j][r] * scl);
        *(short4v*)(dst + base + (size_t)(o & 1023) * NTOK + nbase) = o4;
      }
  } else {                                 // ---- v path ----
    const int idx = bx - 512;
    const int mtile = idx >> 5;            // 8 o-tiles
    const int ntile = idx & 31;            // 32 n-tiles
    gemm_core(Wv + (size_t)mtile * 128 * 256, xTb + (size_t)ntile * 128 * 256,
              256, 256, 256, acc, As, Bs);
#pragma unroll
    for (int i = 0; i < 4; ++i)
#pragma unroll
      for (int j = 0; j < 4; ++j) {
        int rbase = mtile * 128 + wm + i * 16 + ((lane >> 4) << 2);   // o in [0,1024)
        int col   = ntile * 128 + wn + j * 16 + (lane & 15);          // n
        int h = rbase >> 8, c = rbase & 255;
        short4v o4;
#pragma unroll
        for (int r = 0; r < 4; ++r) o4[r] = f2bf(acc[i][j][r]);
        *(short4v*)(vT + ((size_t)(b * 4 + h) * NTOK + col) * 256 + c) = o4;
      }
  }
}

// ---------------- kernel 4: split-K logits partials ----------------
// Lg4[kc][bh][c][d] = sum_{n in chunk kc} q[c][n]*k[d][n]
__global__ void __launch_bounds__(256, 4)
logits_gemm(const short* __restrict__ qb, const short* __restrict__ kb,
            float* __restrict__ Lg4) {
  __shared__ __align__(16) short As[2 * TSZ], Bs[2 * TSZ];
  const int bh = blockIdx.y;
  const int kc    = blockIdx.x & 3;
  const int ntile = (blockIdx.x >> 2) & 1;
  const int mtile = blockIdx.x >> 3;
  const short* Ag = qb + ((size_t)bh * 256 + mtile * 128) * NTOK + kc * 1024;
  const short* Bg = kb + ((size_t)bh * 256 + ntile * 128) * NTOK + kc * 1024;
  f32x4 acc[4][4] = {};
  gemm_core(Ag, Bg, 1024, NTOK, NTOK, acc, As, Bs);

  const int lane = threadIdx.x & 63, wave = threadIdx.x >> 6;
  const int wm = (wave >> 1) * 64, wn = (wave & 1) * 64;
  float* C = Lg4 + ((size_t)kc * 32 + bh) * 65536;
#pragma unroll
  for (int i = 0; i < 4; ++i)
#pragma unroll
    for (int j = 0; j < 4; ++j)
#pragma unroll
      for (int r = 0; r < 4; ++r) {
        int row = mtile * 128 + wm + i * 16 + ((lane >> 4) << 2) + r;
        int col = ntile * 128 + wn + j * 16 + (lane & 15);
        C[(size_t)row * 256 + col] = acc[i][j][r];
      }
}

// ---------------- kernel 5: reduce 4 partials + row softmax, f32 -> bf16 (vectorized) ----------------
__global__ void softmax_k(const float* __restrict__ Lg4, short* __restrict__ P) {
  const int row  = blockIdx.x * 4 + (threadIdx.x >> 6);   // 8192 rows
  const int lane = threadIdx.x & 63;
  const size_t S = (size_t)32 * 65536;
  const float* lr = Lg4 + (size_t)row * 256 + lane * 4;
  f32x4 v = *(const f32x4*)lr;
  {
    f32x4 v1 = *(const f32x4*)(lr + S);
    f32x4 v2 = *(const f32x4*)(lr + 2 * S);
    f32x4 v3 = *(const f32x4*)(lr + 3 * S);
#pragma unroll
    for (int i = 0; i < 4; ++i) v[i] += v1[i] + v2[i] + v3[i];
  }
  float m = fmaxf(fmaxf(v[0], v[1]), fmaxf(v[2], v[3]));
  for (int off = 32; off; off >>= 1) m = fmaxf(m, __shfl_xor(m, off, 64));
  float s = 0.f;
#pragma unroll
  for (int i = 0; i < 4; ++i) { v[i] = __expf(v[i] - m); s += v[i]; }
  for (int off = 32; off; off >>= 1) s += __shfl_xor(s, off, 64);
  const float inv = 1.f / s;
  short4v o4;
#pragma unroll
  for (int i = 0; i < 4; ++i) o4[i] = f2bf(v[i] * inv);
  *(short4v*)(P + (size_t)row * 256 + lane * 4) = o4;
}

// ---------------- kernel 6: att[c][n] = sum_d P[c][d]*v[d][n]; store attT2[b][n][h*256+c] ----------------
__global__ void __launch_bounds__(256, 4)
pv_gemm(const short* __restrict__ P, const short* __restrict__ vT,
        short* __restrict__ attT2) {
  __shared__ __align__(16) short As[2 * TSZ], Bs[2 * TSZ];
  const int bh = blockIdx.y;
  const int b = bh >> 2, h = bh & 3;
  const int bx = xcd_swz(blockIdx.x, 64);
  const int mtile = bx >> 5, ntile = bx & 31;
  const short* Ag = P + (size_t)bh * 65536 + (size_t)mtile * 128 * 256;
  const short* Bg = vT + (size_t)bh * NTOK * 256 + (size_t)(ntile * 128) * 256;
  f32x4 acc[4][4] = {};
  gemm_core(Ag, Bg, 256, 256, 256, acc, As, Bs);

  const int lane = threadIdx.x & 63, wave = threadIdx.x >> 6;
  const int wm = (wave >> 1) * 64, wn = (wave & 1) * 64;
#pragma unroll
  for (int i = 0; i < 4; ++i)
#pragma unroll
    for (int j = 0; j < 4; ++j) {
      int cb = mtile * 128 + wm + i * 16 + ((lane >> 4) << 2);
      int n  = ntile * 128 + wn + j * 16 + (lane & 15);
      short4v o4;
#pragma unroll
      for (int r = 0; r < 4; ++r) o4[r] = f2bf(acc[i][j][r]);
      *(short4v*)(attT2 + (((size_t)b * NTOK + n) * 4 + h) * 256 + cb) = o4;
    }
}

// ---------------- kernel 7: out-proj, A=attT2 (M=n, K=1024), B=WoR2 (N=o) ----------------
__global__ void __launch_bounds__(256, 4)
out_gemm(const short* __restrict__ WoR2, const short* __restrict__ attT2,
         const float* __restrict__ bias, float* __restrict__ out) {
  __shared__ __align__(16) short As[2 * TSZ], Bs[2 * TSZ];
  const int b = blockIdx.y;
  const int mtile = blockIdx.x >> 1;      // 32 n-tiles
  const int ntile = blockIdx.x & 1;       // 2 o-tiles
  const short* Ag = attT2 + ((size_t)b * NTOK + mtile * 128) * 1024;
  const short* Bg = WoR2 + (size_t)ntile * 128 * 1024;
  f32x4 acc[4][4] = {};
  gemm_core(Ag, Bg, 1024, 1024, 1024, acc, As, Bs);

  const int lane = threadIdx.x & 63, wave = threadIdx.x >> 6;
  const int wm = (wave >> 1) * 64, wn = (wave & 1) * 64;
#pragma unroll
  for (int i = 0; i < 4; ++i)
#pragma unroll
    for (int j = 0; j < 4; ++j) {
      int nbase = mtile * 128 + wm + i * 16 + ((lane >> 4) << 2);
      int o     = ntile * 128 + wn + j * 16 + (lane & 15);
      float bo = bias[o];
      f32x4 o4;
#pragma unroll
      for (int r = 0; r < 4; ++r) o4[r] = acc[i][j][r] + bo;
      *(f32x4*)(out + ((size_t)b * 256 + o) * NTOK + nbase) = o4;
    }
}

extern "C" void kernel_launch(void* const* d_in, const int* in_sizes, int n_in,
                              void* d_out, int out_size, void* d_ws, size_t ws_size,
                              hipStream_t stream) {
  (void)in_sizes; (void)n_in; (void)out_size; (void)ws_size;
  const float* x     = (const float*)d_in[0];
  const float* wqkv  = (const float*)d_in[1];
  const float* wout  = (const float*)d_in[2];
  const float* bias  = (const float*)d_in[3];
  float* out = (float*)d_out;

  char* ws = (char*)d_ws;
  size_t off = 0;
  auto alloc = [&](size_t bytes) { char* p = ws + off; off += (bytes + 255) & ~(size_t)255; return p; };

  short* wbf = (short*)alloc((size_t)3072 * 256 * 2);          // 1.6 MB (q,k rows then v rows)
  short* woR2 = (short*)alloc((size_t)256 * 1024 * 2);         // 0.5 MB
  char*  xTr = alloc((size_t)BATCH * NTOK * 256 * 2);          // 16.8 MB
  short* xT  = (short*)xTr;
  short* P   = (short*)xTr;                                    // overlays xT (dead after qkv_fused)
  short* qb  = (short*)alloc((size_t)BATCH * 1024 * NTOK * 2); // 67 MB
  short* attT2 = qb;                                           // overlays q (dead after logits)
  short* kb  = (short*)alloc((size_t)BATCH * 1024 * NTOK * 2); // 67 MB
  short* vT  = (short*)alloc((size_t)BATCH * 1024 * NTOK * 2); // 67 MB
  float* Lg4 = (float*)alloc((size_t)4 * 32 * 65536 * 4);      // 33.6 MB
  // total ws: ~254 MB

  const short* Wqk = wbf;               // rows 0..2047
  const short* Wv  = wbf + (size_t)2048 * 256;

  hipLaunchKernelGGL(prep_w,      dim3(3072),     dim3(256), 0, stream, wqkv, wout, wbf, woR2);
  hipLaunchKernelGGL(transpose_x, dim3(256, 8),   dim3(256), 0, stream, x, xT);
  hipLaunchKernelGGL(qkv_fused,   dim3(768, 8),   dim3(256), 0, stream, Wqk, Wv, xT, qb, kb, vT);
  hipLaunchKernelGGL(logits_gemm, dim3(16, 32),   dim3(256), 0, stream, qb, kb, Lg4);
  hipLaunchKernelGGL(softmax_k,   dim3(2048),     dim3(256), 0, stream, Lg4, P);
  hipLaunchKernelGGL(pv_gemm,     dim3(64, 32),   dim3(256), 0, stream, P, vT, attT2);
  hipLaunchKernelGGL(out_gemm,    dim3(64, 8),    dim3(256), 0, stream, woR2, attT2, bias, out);
}

// Round 13
// 215.322 us; speedup vs baseline: 1.6204x; 1.6204x over previous
//
#include <hip/hip_runtime.h>
#include <stdint.h>

// Problem constants (B, DIM, H, W) = (8, 256, 64, 64), HEADS=4
// Algebraic form: logit_h = scale * Wq_h (x x^T) Wk_h^T ;  out = (sum_h Wo_h S_h Wv_h) x + bias
#define BATCH 8
#define DIM   256
#define NTOK  4096   // H*W
#define GSZ   65536  // 256*256

using bf16x8  = __attribute__((ext_vector_type(8))) __bf16;
using short4v = __attribute__((ext_vector_type(4))) short;
using f32x4   = __attribute__((ext_vector_type(4))) float;

__device__ __forceinline__ short f2bf(float f) {
  union { float f; uint32_t u; } v; v.f = f;
  uint32_t r = v.u + 0x7fffu + ((v.u >> 16) & 1u);   // RNE
  return (short)(r >> 16);
}
__device__ __forceinline__ float bf2f(short s) {
  union { uint32_t u; float f; } v; v.u = ((uint32_t)(uint16_t)s) << 16;
  return v.f;
}

// ---------------- shared GEMM core (2-phase double-buffered) ----------------
// C[128][128] (f32 acc) = A[128 x K] * B[128 x K]^T, both operands K-major bf16.
// 4 waves in 2x2; wave owns 64x64 quadrant (4x4 frags of 16x16).
// mfma_f32_16x16x32_bf16 C/D: row=(l>>4)*4+r, col=l&15  [m89-verified].
#define BK 32
#define TSZ (128 * BK)

__device__ __forceinline__ void stage_tile(const short* g, short* lds, int ld, int tid) {
  const int wave = tid >> 6, lane = tid & 63;
#pragma unroll
  for (int r = 0; r < 2; ++r) {
    const int chunk = wave * 2 + r;                       // 0..7, 16 rows each
    const short* src = g + (size_t)(chunk * 16 + (lane >> 2)) * ld + (lane & 3) * 8;
    __builtin_amdgcn_global_load_lds(
        (const __attribute__((address_space(1))) void*)src,
        (__attribute__((address_space(3))) void*)(lds + chunk * 512),
        16, 0, 0);
  }
}

__device__ __forceinline__ void gemm_core(const short* Ag, const short* Bg, int K,
                                          int lda, int ldb,
                                          f32x4 acc[4][4], short* As, short* Bs) {
  const int tid  = threadIdx.x;
  const int lane = tid & 63;
  const int wave = tid >> 6;
  const int wm = (wave >> 1) * 64, wn = (wave & 1) * 64;
  const int l15 = lane & 15, kg = (lane >> 4) * 8;
  stage_tile(Ag, As, lda, tid);
  stage_tile(Bg, Bs, ldb, tid);
  int cur = 0;
  for (int k0 = 0; k0 < K; k0 += BK) {
    __syncthreads();
    const int nxt = cur ^ 1;
    if (k0 + BK < K) {
      stage_tile(Ag + k0 + BK, As + nxt * TSZ, lda, tid);
      stage_tile(Bg + k0 + BK, Bs + nxt * TSZ, ldb, tid);
    }
    const short* Ac = As + cur * TSZ;
    const short* Bc = Bs + cur * TSZ;
    bf16x8 af[4], bfr[4];
#pragma unroll
    for (int i = 0; i < 4; ++i)
      af[i] = *(const bf16x8*)(Ac + (wm + i * 16 + l15) * BK + kg);
#pragma unroll
    for (int j = 0; j < 4; ++j)
      bfr[j] = *(const bf16x8*)(Bc + (wn + j * 16 + l15) * BK + kg);
#pragma unroll
    for (int i = 0; i < 4; ++i)
#pragma unroll
      for (int j = 0; j < 4; ++j)
        acc[i][j] = __builtin_amdgcn_mfma_f32_16x16x32_bf16(af[i], bfr[j], acc[i][j], 0, 0, 0);
    cur = nxt;
  }
}

// ---------------- kernel 1: weight prep ----------------
// wbf  = bf16 copy of wqkv [3072][256]  (Wq rows 0..1023, Wk rows 1024..2047)
// WoR[h][o][c] = wout[o][c*4+h]       (K-major c)
// WvT[h][j][d] = wqkv[2048+h*256+d][j] (K-major d)
__global__ void prep_w(const float* __restrict__ wqkv, const float* __restrict__ wout,
                       short* __restrict__ wbf, short* __restrict__ WoR,
                       short* __restrict__ WvT) {
  int i = blockIdx.x * 256 + threadIdx.x;
  if (i < 3072 * 256) wbf[i] = f2bf(wqkv[i]);
  if (i < 4 * GSZ) {
    int h = i >> 16, rem = i & 65535;
    { int o = rem >> 8, c = rem & 255;
      WoR[i] = f2bf(wout[o * 1024 + c * 4 + h]); }
    { int j = rem >> 8, d = rem & 255;
      WvT[i] = f2bf(wqkv[(2048 + h * 256 + d) * 256 + j]); }
  }
}

// ---------------- kernel 2: x f32 [b][c][n] -> xb bf16 [b][c][n] + xT bf16 [b][n][c] ----------------
__global__ void __launch_bounds__(256)
xprep(const float* __restrict__ x, short* __restrict__ xb, short* __restrict__ xT) {
  __shared__ short tile[64][68];
  const int b  = blockIdx.y;
  const int c0 = (blockIdx.x >> 6) * 64;
  const int n0 = (blockIdx.x & 63) * 64;
  const int t  = threadIdx.x;
  const float* xp = x + (size_t)b * DIM * NTOK;
  short* xbp = xb + (size_t)b * DIM * NTOK;
#pragma unroll
  for (int r = 0; r < 4; ++r) {
    int c = r * 16 + (t >> 4);
    int n = (t & 15) * 4;
    f32x4 v4 = *(const f32x4*)(xp + (size_t)(c0 + c) * NTOK + n0 + n);
    short4v s4;
#pragma unroll
    for (int u = 0; u < 4; ++u) { s4[u] = f2bf(v4[u]); tile[c][n + u] = s4[u]; }
    *(short4v*)(xbp + (size_t)(c0 + c) * NTOK + n0 + n) = s4;
  }
  __syncthreads();
  short* xo = xT + (size_t)b * NTOK * DIM;
#pragma unroll
  for (int r = 0; r < 4; ++r) {
    int n = r * 16 + (t >> 4);
    int c = (t & 15) * 4;
    short4v o4;
#pragma unroll
    for (int u = 0; u < 4; ++u) o4[u] = tile[c + u][n];
    *(short4v*)(xo + (size_t)(n0 + n) * DIM + c0 + c) = o4;
  }
}

// ---------------- kernel 3: Gram partials Gp[kc][b] = xb(chunk kc) . xb(chunk kc)^T ----------------
__global__ void __launch_bounds__(256, 4)
gram_gemm(const short* __restrict__ xb, float* __restrict__ Gp) {
  __shared__ __align__(16) short As[2 * TSZ], Bs[2 * TSZ];
  const int b = blockIdx.y;
  const int kc = blockIdx.x & 7, tt = blockIdx.x >> 3;
  const int mtile = tt >> 1, ntile = tt & 1;
  const short* base = xb + (size_t)b * DIM * NTOK;
  f32x4 acc[4][4] = {};
  gemm_core(base + (size_t)mtile * 128 * NTOK + kc * 512,
            base + (size_t)ntile * 128 * NTOK + kc * 512,
            512, NTOK, NTOK, acc, As, Bs);
  const int lane = threadIdx.x & 63, wave = threadIdx.x >> 6;
  const int wm = (wave >> 1) * 64, wn = (wave & 1) * 64;
  float* C = Gp + ((size_t)kc * 8 + b) * GSZ;
#pragma unroll
  for (int i = 0; i < 4; ++i)
#pragma unroll
    for (int j = 0; j < 4; ++j)
#pragma unroll
      for (int r = 0; r < 4; ++r) {
        int row = mtile * 128 + wm + i * 16 + ((lane >> 4) << 2) + r;
        int col = ntile * 128 + wn + j * 16 + (lane & 15);
        C[(size_t)row * 256 + col] = acc[i][j][r];
      }
}

// ---------------- kernel 4: reduce 8 partials -> G hi/lo bf16 (compensated split) ----------------
__global__ void gred(const float* __restrict__ Gp, short* __restrict__ Ghi,
                     short* __restrict__ Glo) {
  const int idx = blockIdx.x * 256 + threadIdx.x;     // one f32x4 per thread
  const size_t base = (size_t)idx * 4;
  if (base >= (size_t)BATCH * GSZ) return;
  f32x4 s = {};
#pragma unroll
  for (int kc = 0; kc < 8; ++kc) {
    f32x4 v = *(const f32x4*)(Gp + (size_t)kc * BATCH * GSZ + base);
#pragma unroll
    for (int u = 0; u < 4; ++u) s[u] += v[u];
  }
  short4v hi, lo;
#pragma unroll
  for (int u = 0; u < 4; ++u) {
    hi[u] = f2bf(s[u]);
    lo[u] = f2bf(s[u] - bf2f(hi[u]));
  }
  *(short4v*)(Ghi + base) = hi;
  *(short4v*)(Glo + base) = lo;
}

// ---------------- kernel 5: T1[bh] = Wq_h * G[b]  (G symmetric; hi+lo passes) ----------------
__global__ void __launch_bounds__(256)
t1_gemm(const short* __restrict__ wbf, const short* __restrict__ Ghi,
        const short* __restrict__ Glo, short* __restrict__ T1) {
  __shared__ __align__(16) short As[2 * TSZ], Bs[2 * TSZ];
  const int bh = blockIdx.y, b = bh >> 2, h = bh & 3;
  const int mtile = blockIdx.x >> 1, ntile = blockIdx.x & 1;
  const short* A = wbf + (size_t)(h * 256 + mtile * 128) * 256;   // Wq rows
  f32x4 acc[4][4] = {};
  gemm_core(A, Ghi + (size_t)b * GSZ + (size_t)ntile * 128 * 256, 256, 256, 256, acc, As, Bs);
  gemm_core(A, Glo + (size_t)b * GSZ + (size_t)ntile * 128 * 256, 256, 256, 256, acc, As, Bs);
  const int lane = threadIdx.x & 63, wave = threadIdx.x >> 6;
  const int wm = (wave >> 1) * 64, wn = (wave & 1) * 64;
  short* C = T1 + (size_t)bh * GSZ;
#pragma unroll
  for (int i = 0; i < 4; ++i)
#pragma unroll
    for (int j = 0; j < 4; ++j)
#pragma unroll
      for (int r = 0; r < 4; ++r) {
        int row = mtile * 128 + wm + i * 16 + ((lane >> 4) << 2) + r;
        int col = ntile * 128 + wn + j * 16 + (lane & 15);
        C[(size_t)row * 256 + col] = f2bf(acc[i][j][r]);
      }
}

// ---------------- kernel 6: LT[bh][d][c] = scale * (T1 * Wk_h^T)^T ----------------
__global__ void __launch_bounds__(256)
t2_gemm(const short* __restrict__ wbf, const short* __restrict__ T1,
        float* __restrict__ LT) {
  __shared__ __align__(16) short As[2 * TSZ], Bs[2 * TSZ];
  const int bh = blockIdx.y, h = bh & 3;
  const int mtile = blockIdx.x >> 1, ntile = blockIdx.x & 1;
  f32x4 acc[4][4] = {};
  gemm_core(T1 + (size_t)bh * GSZ + (size_t)mtile * 128 * 256,
            wbf + (size_t)(1024 + h * 256 + ntile * 128) * 256,   // Wk rows
            256, 256, 256, acc, As, Bs);
  const int lane = threadIdx.x & 63, wave = threadIdx.x >> 6;
  const int wm = (wave >> 1) * 64, wn = (wave & 1) * 64;
  float* C = LT + (size_t)bh * GSZ;
#pragma unroll
  for (int i = 0; i < 4; ++i)
#pragma unroll
    for (int j = 0; j < 4; ++j) {
      int cb = mtile * 128 + wm + i * 16 + ((lane >> 4) << 2);     // row (c), 4 consecutive
      int d  = ntile * 128 + wn + j * 16 + (lane & 15);            // col (d)
      f32x4 o4;
#pragma unroll
      for (int r = 0; r < 4; ++r) o4[r] = acc[i][j][r] * 0.0625f;
      *(f32x4*)(C + (size_t)d * 256 + cb) = o4;                    // transposed store
    }
}

// ---------------- kernel 7: column softmax over d: ST[bh][d][c] = softmax_d(LT[.][c]) bf16 ----------------
__global__ void softmax_col(const float* __restrict__ LT, short* __restrict__ ST) {
  const int bh = blockIdx.x, c = threadIdx.x;
  const float* p = LT + (size_t)bh * GSZ + c;
  float m = -1e30f, s = 0.f;
#pragma unroll 4
  for (int d = 0; d < 256; ++d) {
    float v = p[(size_t)d * 256];
    float mn = fmaxf(m, v);
    s = s * __expf(m - mn) + __expf(v - mn);
    m = mn;
  }
  const float inv = 1.f / s;
  short* q = ST + (size_t)bh * GSZ + c;
#pragma unroll 4
  for (int d = 0; d < 256; ++d)
    q[(size_t)d * 256] = f2bf(__expf(p[(size_t)d * 256] - m) * inv);
}

// ---------------- kernel 8: R[bh] = Wo_h * S_h   (B = ST, K-major c) ----------------
__global__ void __launch_bounds__(256)
rh_gemm(const short* __restrict__ WoR, const short* __restrict__ ST,
        short* __restrict__ Rb) {
  __shared__ __align__(16) short As[2 * TSZ], Bs[2 * TSZ];
  const int bh = blockIdx.y, h = bh & 3;
  const int mtile = blockIdx.x >> 1, ntile = blockIdx.x & 1;
  f32x4 acc[4][4] = {};
  gemm_core(WoR + (size_t)h * GSZ + (size_t)mtile * 128 * 256,
            ST + (size_t)bh * GSZ + (size_t)ntile * 128 * 256,
            256, 256, 256, acc, As, Bs);
  const int lane = threadIdx.x & 63, wave = threadIdx.x >> 6;
  const int wm = (wave >> 1) * 64, wn = (wave & 1) * 64;
  short* C = Rb + (size_t)bh * GSZ;
#pragma unroll
  for (int i = 0; i < 4; ++i)
#pragma unroll
    for (int j = 0; j < 4; ++j)
#pragma unroll
      for (int r = 0; r < 4; ++r) {
        int row = mtile * 128 + wm + i * 16 + ((lane >> 4) << 2) + r;
        int col = ntile * 128 + wn + j * 16 + (lane & 15);
        C[(size_t)row * 256 + col] = f2bf(acc[i][j][r]);
      }
}

// ---------------- kernel 9: M[b] = sum_h R[bh] * Wv_h  (B = WvT, K-major d) ----------------
__global__ void __launch_bounds__(256)
mm_gemm(const short* __restrict__ Rb, const short* __restrict__ WvT,
        short* __restrict__ Mb) {
  __shared__ __align__(16) short As[2 * TSZ], Bs[2 * TSZ];
  const int b = blockIdx.y;
  const int mtile = blockIdx.x >> 1, ntile = blockIdx.x & 1;
  f32x4 acc[4][4] = {};
  for (int h = 0; h < 4; ++h)
    gemm_core(Rb + (size_t)(b * 4 + h) * GSZ + (size_t)mtile * 128 * 256,
              WvT + (size_t)h * GSZ + (size_t)ntile * 128 * 256,
              256, 256, 256, acc, As, Bs);
  const int lane = threadIdx.x & 63, wave = threadIdx.x >> 6;
  const int wm = (wave >> 1) * 64, wn = (wave & 1) * 64;
  short* C = Mb + (size_t)b * GSZ;
#pragma unroll
  for (int i = 0; i < 4; ++i)
#pragma unroll
    for (int j = 0; j < 4; ++j)
#pragma unroll
      for (int r = 0; r < 4; ++r) {
        int row = mtile * 128 + wm + i * 16 + ((lane >> 4) << 2) + r;
        int col = ntile * 128 + wn + j * 16 + (lane & 15);
        C[(size_t)row * 256 + col] = f2bf(acc[i][j][r]);
      }
}

// ---------------- kernel 10: out[b][o][n] = sum_j M[o][j] x[j][n] + bias[o] ----------------
// C[n][o] via A=xT (rows n), B=Mb (rows o); frag holds 4 consecutive n -> float4 stores.
__global__ void __launch_bounds__(256, 4)
final_gemm(const short* __restrict__ xT, const short* __restrict__ Mb,
           const float* __restrict__ bias, float* __restrict__ out) {
  __shared__ __align__(16) short As[2 * TSZ], Bs[2 * TSZ];
  const int b = blockIdx.y;
  const int mtile = blockIdx.x >> 1;      // 32 n-tiles
  const int ntile = blockIdx.x & 1;       // 2 o-tiles
  f32x4 acc[4][4] = {};
  gemm_core(xT + (size_t)b * NTOK * DIM + (size_t)mtile * 128 * 256,
            Mb + (size_t)b * GSZ + (size_t)ntile * 128 * 256,
            256, 256, 256, acc, As, Bs);
  const int lane = threadIdx.x & 63, wave = threadIdx.x >> 6;
  const int wm = (wave >> 1) * 64, wn = (wave & 1) * 64;
#pragma unroll
  for (int i = 0; i < 4; ++i)
#pragma unroll
    for (int j = 0; j < 4; ++j) {
      int nbase = mtile * 128 + wm + i * 16 + ((lane >> 4) << 2);
      int o     = ntile * 128 + wn + j * 16 + (lane & 15);
      float bo = bias[o];
      f32x4 o4;
#pragma unroll
      for (int r = 0; r < 4; ++r) o4[r] = acc[i][j][r] + bo;
      *(f32x4*)(out + ((size_t)b * 256 + o) * NTOK + nbase) = o4;
    }
}

extern "C" void kernel_launch(void* const* d_in, const int* in_sizes, int n_in,
                              void* d_out, int out_size, void* d_ws, size_t ws_size,
                              hipStream_t stream) {
  (void)in_sizes; (void)n_in; (void)out_size; (void)ws_size;
  const float* x     = (const float*)d_in[0];
  const float* wqkv  = (const float*)d_in[1];
  const float* wout  = (const float*)d_in[2];
  const float* bias  = (const float*)d_in[3];
  float* out = (float*)d_out;

  char* ws = (char*)d_ws;
  size_t off = 0;
  auto alloc = [&](size_t bytes) { char* p = ws + off; off += (bytes + 255) & ~(size_t)255; return p; };

  short* wbf = (short*)alloc((size_t)3072 * 256 * 2);            // 1.6 MB
  short* WoR = (short*)alloc((size_t)4 * GSZ * 2);               // 0.5 MB
  short* WvT = (short*)alloc((size_t)4 * GSZ * 2);               // 0.5 MB
  short* xb  = (short*)alloc((size_t)BATCH * DIM * NTOK * 2);    // 16.8 MB
  short* xT  = (short*)alloc((size_t)BATCH * NTOK * DIM * 2);    // 16.8 MB
  float* Gp  = (float*)alloc((size_t)8 * BATCH * GSZ * 4);       // 16.8 MB
  short* Ghi = (short*)alloc((size_t)BATCH * GSZ * 2);           // 1.05 MB
  short* Glo = (short*)alloc((size_t)BATCH * GSZ * 2);           // 1.05 MB
  short* T1  = (short*)alloc((size_t)32 * GSZ * 2);              // 4.2 MB
  float* LT  = (float*)alloc((size_t)32 * GSZ * 4);              // 8.4 MB
  short* ST  = (short*)alloc((size_t)32 * GSZ * 2);              // 4.2 MB
  short* Rb  = (short*)alloc((size_t)32 * GSZ * 2);              // 4.2 MB
  short* Mb  = (short*)alloc((size_t)BATCH * GSZ * 2);           // 1.05 MB
  // total ws: ~77 MB

  hipLaunchKernelGGL(prep_w,      dim3(3072),    dim3(256), 0, stream, wqkv, wout, wbf, WoR, WvT);
  hipLaunchKernelGGL(xprep,       dim3(256, 8),  dim3(256), 0, stream, x, xb, xT);
  hipLaunchKernelGGL(gram_gemm,   dim3(32, 8),   dim3(256), 0, stream, xb, Gp);
  hipLaunchKernelGGL(gred,        dim3(512),     dim3(256), 0, stream, Gp, Ghi, Glo);
  hipLaunchKernelGGL(t1_gemm,     dim3(4, 32),   dim3(256), 0, stream, wbf, Ghi, Glo, T1);
  hipLaunchKernelGGL(t2_gemm,     dim3(4, 32),   dim3(256), 0, stream, wbf, T1, LT);
  hipLaunchKernelGGL(softmax_col, dim3(32),      dim3(256), 0, stream, LT, ST);
  hipLaunchKernelGGL(rh_gemm,     dim3(4, 32),   dim3(256), 0, stream, WoR, ST, Rb);
  hipLaunchKernelGGL(mm_gemm,     dim3(4, 8),    dim3(256), 0, stream, Rb, WvT, Mb);
  hipLaunchKernelGGL(final_gemm,  dim3(64, 8),   dim3(256), 0, stream, xT, Mb, bias, out);
}

// Round 14
// 179.629 us; speedup vs baseline: 1.9423x; 1.1987x over previous
//
#include <hip/hip_runtime.h>
#include <stdint.h>

// Problem constants (B, DIM, H, W) = (8, 256, 64, 64), HEADS=4
// Algebraic form: logit_h = scale * Wq_h (x x^T) Wk_h^T ;  out = (sum_h Wo_h S_h Wv_h) x + bias
#define BATCH 8
#define DIM   256
#define NTOK  4096   // H*W
#define GSZ   65536  // 256*256

using bf16x8  = __attribute__((ext_vector_type(8))) __bf16;
using short4v = __attribute__((ext_vector_type(4))) short;
using f32x4   = __attribute__((ext_vector_type(4))) float;

__device__ __forceinline__ short f2bf(float f) {
  union { float f; uint32_t u; } v; v.f = f;
  uint32_t r = v.u + 0x7fffu + ((v.u >> 16) & 1u);   // RNE
  return (short)(r >> 16);
}
__device__ __forceinline__ float bf2f(short s) {
  union { uint32_t u; float f; } v; v.u = ((uint32_t)(uint16_t)s) << 16;
  return v.f;
}

// ---------------- shared GEMM core (2-phase double-buffered) ----------------
// C[128][128] (f32 acc) = A[128 x K] * B[128 x K]^T, both operands K-major bf16.
// 4 waves in 2x2; wave owns 64x64 quadrant (4x4 frags of 16x16).
// mfma_f32_16x16x32_bf16 C/D: row=(l>>4)*4+r, col=l&15  [m89-verified].
#define BK 32
#define TSZ (128 * BK)

__device__ __forceinline__ void stage_tile(const short* g, short* lds, int ld, int tid) {
  const int wave = tid >> 6, lane = tid & 63;
#pragma unroll
  for (int r = 0; r < 2; ++r) {
    const int chunk = wave * 2 + r;                       // 0..7, 16 rows each
    const short* src = g + (size_t)(chunk * 16 + (lane >> 2)) * ld + (lane & 3) * 8;
    __builtin_amdgcn_global_load_lds(
        (const __attribute__((address_space(1))) void*)src,
        (__attribute__((address_space(3))) void*)(lds + chunk * 512),
        16, 0, 0);
  }
}

__device__ __forceinline__ void gemm_core(const short* Ag, const short* Bg, int K,
                                          int lda, int ldb,
                                          f32x4 acc[4][4], short* As, short* Bs) {
  const int tid  = threadIdx.x;
  const int lane = tid & 63;
  const int wave = tid >> 6;
  const int wm = (wave >> 1) * 64, wn = (wave & 1) * 64;
  const int l15 = lane & 15, kg = (lane >> 4) * 8;
  stage_tile(Ag, As, lda, tid);
  stage_tile(Bg, Bs, ldb, tid);
  int cur = 0;
  for (int k0 = 0; k0 < K; k0 += BK) {
    __syncthreads();
    const int nxt = cur ^ 1;
    if (k0 + BK < K) {
      stage_tile(Ag + k0 + BK, As + nxt * TSZ, lda, tid);
      stage_tile(Bg + k0 + BK, Bs + nxt * TSZ, ldb, tid);
    }
    const short* Ac = As + cur * TSZ;
    const short* Bc = Bs + cur * TSZ;
    bf16x8 af[4], bfr[4];
#pragma unroll
    for (int i = 0; i < 4; ++i)
      af[i] = *(const bf16x8*)(Ac + (wm + i * 16 + l15) * BK + kg);
#pragma unroll
    for (int j = 0; j < 4; ++j)
      bfr[j] = *(const bf16x8*)(Bc + (wn + j * 16 + l15) * BK + kg);
#pragma unroll
    for (int i = 0; i < 4; ++i)
#pragma unroll
      for (int j = 0; j < 4; ++j)
        acc[i][j] = __builtin_amdgcn_mfma_f32_16x16x32_bf16(af[i], bfr[j], acc[i][j], 0, 0, 0);
    cur = nxt;
  }
}

// ---------------- kernel 1: weight prep ----------------
// wbf  = bf16 copy of wqkv [3072][256]  (Wq rows 0..1023, Wk rows 1024..2047)
// WoR[h][o][c] = wout[o][c*4+h]       (K-major c)
// WvT[h][j][d] = wqkv[2048+h*256+d][j] (K-major d)
__global__ void prep_w(const float* __restrict__ wqkv, const float* __restrict__ wout,
                       short* __restrict__ wbf, short* __restrict__ WoR,
                       short* __restrict__ WvT) {
  int i = blockIdx.x * 256 + threadIdx.x;
  if (i < 3072 * 256) wbf[i] = f2bf(wqkv[i]);
  if (i < 4 * GSZ) {
    int h = i >> 16, rem = i & 65535;
    { int o = rem >> 8, c = rem & 255;
      WoR[i] = f2bf(wout[o * 1024 + c * 4 + h]); }
    { int j = rem >> 8, d = rem & 255;
      WvT[i] = f2bf(wqkv[(2048 + h * 256 + d) * 256 + j]); }
  }
}

// ---------------- kernel 2: x f32 [b][c][n] -> xb bf16 [b][c][n] + xT bf16 [b][n][c] ----------------
__global__ void __launch_bounds__(256)
xprep(const float* __restrict__ x, short* __restrict__ xb, short* __restrict__ xT) {
  __shared__ short tile[64][68];
  const int b  = blockIdx.y;
  const int c0 = (blockIdx.x >> 6) * 64;
  const int n0 = (blockIdx.x & 63) * 64;
  const int t  = threadIdx.x;
  const float* xp = x + (size_t)b * DIM * NTOK;
  short* xbp = xb + (size_t)b * DIM * NTOK;
#pragma unroll
  for (int r = 0; r < 4; ++r) {
    int c = r * 16 + (t >> 4);
    int n = (t & 15) * 4;
    f32x4 v4 = *(const f32x4*)(xp + (size_t)(c0 + c) * NTOK + n0 + n);
    short4v s4;
#pragma unroll
    for (int u = 0; u < 4; ++u) { s4[u] = f2bf(v4[u]); tile[c][n + u] = s4[u]; }
    *(short4v*)(xbp + (size_t)(c0 + c) * NTOK + n0 + n) = s4;
  }
  __syncthreads();
  short* xo = xT + (size_t)b * NTOK * DIM;
#pragma unroll
  for (int r = 0; r < 4; ++r) {
    int n = r * 16 + (t >> 4);
    int c = (t & 15) * 4;
    short4v o4;
#pragma unroll
    for (int u = 0; u < 4; ++u) o4[u] = tile[c + u][n];
    *(short4v*)(xo + (size_t)(n0 + n) * DIM + c0 + c) = o4;
  }
}

// ---------------- kernel 3: Gram partials Gp[kc][b] = xb(chunk kc) . xb(chunk kc)^T ----------------
__global__ void __launch_bounds__(256, 4)
gram_gemm(const short* __restrict__ xb, float* __restrict__ Gp) {
  __shared__ __align__(16) short As[2 * TSZ], Bs[2 * TSZ];
  const int b = blockIdx.y;
  const int kc = blockIdx.x & 7, tt = blockIdx.x >> 3;
  const int mtile = tt >> 1, ntile = tt & 1;
  const short* base = xb + (size_t)b * DIM * NTOK;
  f32x4 acc[4][4] = {};
  gemm_core(base + (size_t)mtile * 128 * NTOK + kc * 512,
            base + (size_t)ntile * 128 * NTOK + kc * 512,
            512, NTOK, NTOK, acc, As, Bs);
  const int lane = threadIdx.x & 63, wave = threadIdx.x >> 6;
  const int wm = (wave >> 1) * 64, wn = (wave & 1) * 64;
  float* C = Gp + ((size_t)kc * 8 + b) * GSZ;
#pragma unroll
  for (int i = 0; i < 4; ++i)
#pragma unroll
    for (int j = 0; j < 4; ++j)
#pragma unroll
      for (int r = 0; r < 4; ++r) {
        int row = mtile * 128 + wm + i * 16 + ((lane >> 4) << 2) + r;
        int col = ntile * 128 + wn + j * 16 + (lane & 15);
        C[(size_t)row * 256 + col] = acc[i][j][r];
      }
}

// ---------------- kernel 4: reduce 8 partials -> G hi/lo bf16 (compensated split) ----------------
__global__ void gred(const float* __restrict__ Gp, short* __restrict__ Ghi,
                     short* __restrict__ Glo) {
  const int idx = blockIdx.x * 256 + threadIdx.x;     // one f32x4 per thread
  const size_t base = (size_t)idx * 4;
  if (base >= (size_t)BATCH * GSZ) return;
  f32x4 s = {};
#pragma unroll
  for (int kc = 0; kc < 8; ++kc) {
    f32x4 v = *(const f32x4*)(Gp + (size_t)kc * BATCH * GSZ + base);
#pragma unroll
    for (int u = 0; u < 4; ++u) s[u] += v[u];
  }
  short4v hi, lo;
#pragma unroll
  for (int u = 0; u < 4; ++u) {
    hi[u] = f2bf(s[u]);
    lo[u] = f2bf(s[u] - bf2f(hi[u]));
  }
  *(short4v*)(Ghi + base) = hi;
  *(short4v*)(Glo + base) = lo;
}

// ---------------- kernel 5: T1[bh] = Wq_h * G[b]  (G symmetric; hi+lo passes) ----------------
__global__ void __launch_bounds__(256)
t1_gemm(const short* __restrict__ wbf, const short* __restrict__ Ghi,
        const short* __restrict__ Glo, short* __restrict__ T1) {
  __shared__ __align__(16) short As[2 * TSZ], Bs[2 * TSZ];
  const int bh = blockIdx.y, b = bh >> 2, h = bh & 3;
  const int mtile = blockIdx.x >> 1, ntile = blockIdx.x & 1;
  const short* A = wbf + (size_t)(h * 256 + mtile * 128) * 256;   // Wq rows
  f32x4 acc[4][4] = {};
  gemm_core(A, Ghi + (size_t)b * GSZ + (size_t)ntile * 128 * 256, 256, 256, 256, acc, As, Bs);
  gemm_core(A, Glo + (size_t)b * GSZ + (size_t)ntile * 128 * 256, 256, 256, 256, acc, As, Bs);
  const int lane = threadIdx.x & 63, wave = threadIdx.x >> 6;
  const int wm = (wave >> 1) * 64, wn = (wave & 1) * 64;
  short* C = T1 + (size_t)bh * GSZ;
#pragma unroll
  for (int i = 0; i < 4; ++i)
#pragma unroll
    for (int j = 0; j < 4; ++j)
#pragma unroll
      for (int r = 0; r < 4; ++r) {
        int row = mtile * 128 + wm + i * 16 + ((lane >> 4) << 2) + r;
        int col = ntile * 128 + wn + j * 16 + (lane & 15);
        C[(size_t)row * 256 + col] = f2bf(acc[i][j][r]);
      }
}

// ---------------- kernel 6: LT[bh][d][c] = scale * (T1 * Wk_h^T)^T ----------------
__global__ void __launch_bounds__(256)
t2_gemm(const short* __restrict__ wbf, const short* __restrict__ T1,
        float* __restrict__ LT) {
  __shared__ __align__(16) short As[2 * TSZ], Bs[2 * TSZ];
  const int bh = blockIdx.y, h = bh & 3;
  const int mtile = blockIdx.x >> 1, ntile = blockIdx.x & 1;
  f32x4 acc[4][4] = {};
  gemm_core(T1 + (size_t)bh * GSZ + (size_t)mtile * 128 * 256,
            wbf + (size_t)(1024 + h * 256 + ntile * 128) * 256,   // Wk rows
            256, 256, 256, acc, As, Bs);
  const int lane = threadIdx.x & 63, wave = threadIdx.x >> 6;
  const int wm = (wave >> 1) * 64, wn = (wave & 1) * 64;
  float* C = LT + (size_t)bh * GSZ;
#pragma unroll
  for (int i = 0; i < 4; ++i)
#pragma unroll
    for (int j = 0; j < 4; ++j) {
      int cb = mtile * 128 + wm + i * 16 + ((lane >> 4) << 2);     // row (c), 4 consecutive
      int d  = ntile * 128 + wn + j * 16 + (lane & 15);            // col (d)
      f32x4 o4;
#pragma unroll
      for (int r = 0; r < 4; ++r) o4[r] = acc[i][j][r] * 0.0625f;
      *(f32x4*)(C + (size_t)d * 256 + cb) = o4;                    // transposed store
    }
}

// ---------------- kernel 7: column softmax over d (wave-parallel) ----------------
// ST[bh][d][c] = softmax_d(LT[bh][.][c]) bf16.
// Block = 64 columns x 4 d-groups (256 thr); each thread reduces 64 d-values in
// registers; 4-way cross-wave combine via LDS. Loads/stores lane-coalesced.
__global__ void __launch_bounds__(256)
softmax_col(const float* __restrict__ LT, short* __restrict__ ST) {
  __shared__ float red[2][4][64];
  const int bh = blockIdx.y;
  const int cc = threadIdx.x & 63;
  const int dg = threadIdx.x >> 6;                    // 0..3 (= wave id)
  const int c  = blockIdx.x * 64 + cc;
  const float* p = LT + (size_t)bh * GSZ + c;
  float v[64];
  float m = -1e30f;
#pragma unroll
  for (int i = 0; i < 64; ++i) {
    v[i] = p[(size_t)(dg * 64 + i) * 256];
    m = fmaxf(m, v[i]);
  }
  red[0][dg][cc] = m;
  __syncthreads();
  m = fmaxf(fmaxf(red[0][0][cc], red[0][1][cc]),
            fmaxf(red[0][2][cc], red[0][3][cc]));
  float s = 0.f;
#pragma unroll
  for (int i = 0; i < 64; ++i) { v[i] = __expf(v[i] - m); s += v[i]; }
  red[1][dg][cc] = s;
  __syncthreads();
  s = red[1][0][cc] + red[1][1][cc] + red[1][2][cc] + red[1][3][cc];
  const float inv = 1.f / s;
  short* q = ST + (size_t)bh * GSZ + c;
#pragma unroll
  for (int i = 0; i < 64; ++i)
    q[(size_t)(dg * 64 + i) * 256] = f2bf(v[i] * inv);
}

// ---------------- kernel 8: R[bh] = Wo_h * S_h   (B = ST, K-major c) ----------------
__global__ void __launch_bounds__(256)
rh_gemm(const short* __restrict__ WoR, const short* __restrict__ ST,
        short* __restrict__ Rb) {
  __shared__ __align__(16) short As[2 * TSZ], Bs[2 * TSZ];
  const int bh = blockIdx.y, h = bh & 3;
  const int mtile = blockIdx.x >> 1, ntile = blockIdx.x & 1;
  f32x4 acc[4][4] = {};
  gemm_core(WoR + (size_t)h * GSZ + (size_t)mtile * 128 * 256,
            ST + (size_t)bh * GSZ + (size_t)ntile * 128 * 256,
            256, 256, 256, acc, As, Bs);
  const int lane = threadIdx.x & 63, wave = threadIdx.x >> 6;
  const int wm = (wave >> 1) * 64, wn = (wave & 1) * 64;
  short* C = Rb + (size_t)bh * GSZ;
#pragma unroll
  for (int i = 0; i < 4; ++i)
#pragma unroll
    for (int j = 0; j < 4; ++j)
#pragma unroll
      for (int r = 0; r < 4; ++r) {
        int row = mtile * 128 + wm + i * 16 + ((lane >> 4) << 2) + r;
        int col = ntile * 128 + wn + j * 16 + (lane & 15);
        C[(size_t)row * 256 + col] = f2bf(acc[i][j][r]);
      }
}

// ---------------- kernel 9: M[b] = sum_h R[bh] * Wv_h  (B = WvT, K-major d) ----------------
__global__ void __launch_bounds__(256)
mm_gemm(const short* __restrict__ Rb, const short* __restrict__ WvT,
        short* __restrict__ Mb) {
  __shared__ __align__(16) short As[2 * TSZ], Bs[2 * TSZ];
  const int b = blockIdx.y;
  const int mtile = blockIdx.x >> 1, ntile = blockIdx.x & 1;
  f32x4 acc[4][4] = {};
  for (int h = 0; h < 4; ++h)
    gemm_core(Rb + (size_t)(b * 4 + h) * GSZ + (size_t)mtile * 128 * 256,
              WvT + (size_t)h * GSZ + (size_t)ntile * 128 * 256,
              256, 256, 256, acc, As, Bs);
  const int lane = threadIdx.x & 63, wave = threadIdx.x >> 6;
  const int wm = (wave >> 1) * 64, wn = (wave & 1) * 64;
  short* C = Mb + (size_t)b * GSZ;
#pragma unroll
  for (int i = 0; i < 4; ++i)
#pragma unroll
    for (int j = 0; j < 4; ++j)
#pragma unroll
      for (int r = 0; r < 4; ++r) {
        int row = mtile * 128 + wm + i * 16 + ((lane >> 4) << 2) + r;
        int col = ntile * 128 + wn + j * 16 + (lane & 15);
        C[(size_t)row * 256 + col] = f2bf(acc[i][j][r]);
      }
}

// ---------------- kernel 10: out[b][o][n] = sum_j M[o][j] x[j][n] + bias[o] ----------------
// C[n][o] via A=xT (rows n), B=Mb (rows o); frag holds 4 consecutive n -> float4 stores.
__global__ void __launch_bounds__(256, 4)
final_gemm(const short* __restrict__ xT, const short* __restrict__ Mb,
           const float* __restrict__ bias, float* __restrict__ out) {
  __shared__ __align__(16) short As[2 * TSZ], Bs[2 * TSZ];
  const int b = blockIdx.y;
  const int mtile = blockIdx.x >> 1;      // 32 n-tiles
  const int ntile = blockIdx.x & 1;       // 2 o-tiles
  f32x4 acc[4][4] = {};
  gemm_core(xT + (size_t)b * NTOK * DIM + (size_t)mtile * 128 * 256,
            Mb + (size_t)b * GSZ + (size_t)ntile * 128 * 256,
            256, 256, 256, acc, As, Bs);
  const int lane = threadIdx.x & 63, wave = threadIdx.x >> 6;
  const int wm = (wave >> 1) * 64, wn = (wave & 1) * 64;
#pragma unroll
  for (int i = 0; i < 4; ++i)
#pragma unroll
    for (int j = 0; j < 4; ++j) {
      int nbase = mtile * 128 + wm + i * 16 + ((lane >> 4) << 2);
      int o     = ntile * 128 + wn + j * 16 + (lane & 15);
      float bo = bias[o];
      f32x4 o4;
#pragma unroll
      for (int r = 0; r < 4; ++r) o4[r] = acc[i][j][r] + bo;
      *(f32x4*)(out + ((size_t)b * 256 + o) * NTOK + nbase) = o4;
    }
}

extern "C" void kernel_launch(void* const* d_in, const int* in_sizes, int n_in,
                              void* d_out, int out_size, void* d_ws, size_t ws_size,
                              hipStream_t stream) {
  (void)in_sizes; (void)n_in; (void)out_size; (void)ws_size;
  const float* x     = (const float*)d_in[0];
  const float* wqkv  = (const float*)d_in[1];
  const float* wout  = (const float*)d_in[2];
  const float* bias  = (const float*)d_in[3];
  float* out = (float*)d_out;

  char* ws = (char*)d_ws;
  size_t off = 0;
  auto alloc = [&](size_t bytes) { char* p = ws + off; off += (bytes + 255) & ~(size_t)255; return p; };

  short* wbf = (short*)alloc((size_t)3072 * 256 * 2);            // 1.6 MB
  short* WoR = (short*)alloc((size_t)4 * GSZ * 2);               // 0.5 MB
  short* WvT = (short*)alloc((size_t)4 * GSZ * 2);               // 0.5 MB
  short* xb  = (short*)alloc((size_t)BATCH * DIM * NTOK * 2);    // 16.8 MB
  short* xT  = (short*)alloc((size_t)BATCH * NTOK * DIM * 2);    // 16.8 MB
  float* Gp  = (float*)alloc((size_t)8 * BATCH * GSZ * 4);       // 16.8 MB
  short* Ghi = (short*)alloc((size_t)BATCH * GSZ * 2);           // 1.05 MB
  short* Glo = (short*)alloc((size_t)BATCH * GSZ * 2);           // 1.05 MB
  short* T1  = (short*)alloc((size_t)32 * GSZ * 2);              // 4.2 MB
  float* LT  = (float*)alloc((size_t)32 * GSZ * 4);              // 8.4 MB
  short* ST  = (short*)alloc((size_t)32 * GSZ * 2);              // 4.2 MB
  short* Rb  = (short*)alloc((size_t)32 * GSZ * 2);              // 4.2 MB
  short* Mb  = (short*)alloc((size_t)BATCH * GSZ * 2);           // 1.05 MB
  // total ws: ~77 MB

  hipLaunchKernelGGL(prep_w,      dim3(3072),    dim3(256), 0, stream, wqkv, wout, wbf, WoR, WvT);
  hipLaunchKernelGGL(xprep,       dim3(256, 8),  dim3(256), 0, stream, x, xb, xT);
  hipLaunchKernelGGL(gram_gemm,   dim3(32, 8),   dim3(256), 0, stream, xb, Gp);
  hipLaunchKernelGGL(gred,        dim3(512),     dim3(256), 0, stream, Gp, Ghi, Glo);
  hipLaunchKernelGGL(t1_gemm,     dim3(4, 32),   dim3(256), 0, stream, wbf, Ghi, Glo, T1);
  hipLaunchKernelGGL(t2_gemm,     dim3(4, 32),   dim3(256), 0, stream, wbf, T1, LT);
  hipLaunchKernelGGL(softmax_col, dim3(4, 32),   dim3(256), 0, stream, LT, ST);
  hipLaunchKernelGGL(rh_gemm,     dim3(4, 32),   dim3(256), 0, stream, WoR, ST, Rb);
  hipLaunchKernelGGL(mm_gemm,     dim3(4, 8),    dim3(256), 0, stream, Rb, WvT, Mb);
  hipLaunchKernelGGL(final_gemm,  dim3(64, 8),   dim3(256), 0, stream, xT, Mb, bias, out);
}